// Round 3
// baseline (178.173 us; speedup 1.0000x reference)
//
#include <hip/hip_runtime.h>

// Problem constants (frozen by the reference)
#define NN 16
#define CC 64
#define HH 128
#define WW 128

#define LDS_STRIDE 72    // bf16 elems per xsT row (144 B; dword stride 36)

typedef __attribute__((ext_vector_type(8))) short short8;   // bf16x8 (4 VGPRs)
typedef __attribute__((ext_vector_type(4))) float floatx4;  // MFMA C/D

__device__ __forceinline__ short f2bf(float f) {
    union { float f; unsigned u; } v; v.f = f;
    unsigned r = v.u + 0x7fffu + ((v.u >> 16) & 1u);
    return (short)(r >> 16);
}
__device__ __forceinline__ unsigned pack2bf(float lo, float hi) {
    union { float f; unsigned u; } a, b; a.f = lo; b.f = hi;
    unsigned ra = a.u + 0x7fffu + ((a.u >> 16) & 1u);
    unsigned rb = b.u + 0x7fffu + ((b.u >> 16) & 1u);
    return (ra >> 16) | (rb & 0xffff0000u);
}
__device__ __forceinline__ float bf2f(unsigned short u) {
    union { unsigned u; float f; } v; v.u = ((unsigned)u) << 16;
    return v.f;
}

// ---------------------------------------------------------------------------
// Kernel 0: w3 (co, ci, 1, 5) fp32 -> Abf[co][kk] bf16, kk = tap*64 + ci.
// Also zeroes the 256 B zero-page used by combine's OOB window loads
// (d_ws is re-poisoned before every launch, so rewrite every call).
// ---------------------------------------------------------------------------
__global__ __launch_bounds__(256) void prep_w(const float* __restrict__ w3,
                                              short* __restrict__ Abf,
                                              float* __restrict__ zp) {
    int idx = blockIdx.x * 256 + threadIdx.x;
    if (idx < CC * CC * 5) {
        int tap = idx % 5;
        int ci  = (idx / 5) % CC;
        int co  = idx / (5 * CC);
        Abf[co * 320 + tap * 64 + ci] = f2bf(w3[idx]);
    }
    if (blockIdx.x == 0 && threadIdx.x < 64) zp[threadIdx.x] = 0.f;
}

// ---------------------------------------------------------------------------
// Kernel 1: t3 GEMM. One block per (n,h) row; LDS 19008 B -> 8 blocks/CU.
// Phase 1: stage x row transposed bf16, packed ci-pairs (conflict-free b32).
// Phase 2: MFMA, 2x2 wave split (halves per-wave LDS B reads; R1-proven).
// Store: t3[n][co][h][w] bf16 -> the FIRST 256 B of out's 512 B row slot
//   (short index ((n*64+co)*128+h)*256 + w). combine overwrites the full
//   slot afterwards; its reads of the slot precede its writes per-thread.
// ---------------------------------------------------------------------------
__global__ __launch_bounds__(256, 8) void t3gemm(const float* __restrict__ x,
                                                 const short* __restrict__ Abf,
                                                 float* __restrict__ out) {
    __shared__ __align__(16) char smem[132 * LDS_STRIDE * 2];  // 19008 B
    short*    xsT = (short*)smem;
    unsigned* xsW = (unsigned*)smem;   // dword view, stride 36

    const int bid = blockIdx.x;
    const int nh  = ((bid & 7) << 8) | (bid >> 3);   // XCD-contiguous h
    const int n   = nh >> 7;
    const int h   = nh & (HH - 1);
    const int tid = threadIdx.x;

    // ---- Phase 1: each thread owns ci-pair cp and w-strip wqg*16..+15 ----
    const float* xbase = x + (((size_t)n * CC) * HH + h) * WW;
    {
        const int cp  = tid & 31;       // ci pair: rows 2cp, 2cp+1
        const int wqg = tid >> 5;       // 0..7 -> w = wqg*16 .. +15
        const float* r0 = xbase + (size_t)(2 * cp) * (HH * WW);
        const float* r1 = r0 + HH * WW;
        #pragma unroll
        for (int q = 0; q < 4; ++q) {
            int wq = wqg * 4 + q;
            float4 a = *(const float4*)(r0 + wq * 4);
            float4 b = *(const float4*)(r1 + wq * 4);
            int wp = wq * 4 + 2;
            xsW[(wp + 0) * 36 + cp] = pack2bf(a.x, b.x);
            xsW[(wp + 1) * 36 + cp] = pack2bf(a.y, b.y);
            xsW[(wp + 2) * 36 + cp] = pack2bf(a.z, b.z);
            xsW[(wp + 3) * 36 + cp] = pack2bf(a.w, b.w);
        }
        if (tid < 128) {    // zero pad rows wp in {0,1,130,131}
            int wpi = tid >> 5;
            int wpz = (wpi < 2) ? wpi : 128 + wpi;
            xsW[wpz * 36 + (tid & 31)] = 0u;
        }
    }
    __syncthreads();

    // ---- Phase 2: MFMA, 2x2 wave split ----
    const int lane = tid & 63;
    const int W    = tid >> 6;
    const int lm   = lane & 15;
    const int g    = lane >> 4;
    const int mh   = W >> 1;         // co half: co-tiles {2mh, 2mh+1}
    const int wh   = W & 1;          // w half:  j-tiles wh*4 .. wh*4+3

    floatx4 acc[2][4];
    #pragma unroll
    for (int m = 0; m < 2; ++m)
        #pragma unroll
        for (int j = 0; j < 4; ++j) acc[m][j] = (floatx4){0.f, 0.f, 0.f, 0.f};

    const short* arow = Abf + (mh * 32 + lm) * 320;

    for (int ks = 0; ks < 10; ++ks) {
        const int kbase = ks * 32 + g * 8;
        const int tap   = kbase >> 6;
        const int cib   = kbase & 63;

        short8 a0 = *(const short8*)(arow + kbase);
        short8 a1 = *(const short8*)(arow + 16 * 320 + kbase);
        #pragma unroll
        for (int j = 0; j < 4; ++j) {
            int wp = (wh * 4 + j) * 16 + lm + tap;
            short8 b = *(const short8*)&xsT[wp * LDS_STRIDE + cib];
            acc[0][j] = __builtin_amdgcn_mfma_f32_16x16x32_bf16(a0, b, acc[0][j], 0, 0, 0);
            acc[1][j] = __builtin_amdgcn_mfma_f32_16x16x32_bf16(a1, b, acc[1][j], 0, 0, 0);
        }
    }

    // ---- Store t3 (bf16) into out's row slots ----
    short* t3s = (short*)out;
    #pragma unroll
    for (int m = 0; m < 2; ++m)
        #pragma unroll
        for (int j = 0; j < 4; ++j)
            #pragma unroll
            for (int r = 0; r < 4; ++r) {
                int co = (mh * 2 + m) * 16 + g * 4 + r;
                int w  = (wh * 4 + j) * 16 + lm;
                t3s[((size_t)(n * CC + co) * HH + h) * 256 + w] = f2bf(acc[m][j][r]);
            }
}

// ---------------------------------------------------------------------------
// Kernel 2: combine. One block per (n,h) row. NO LDS, NO barriers -> deep
// TLP hides the window-load latency the megakernel couldn't. Thread owns
// (chi = tid>>5, w0 = (tid&31)*4); iterates c = it*8 + chi, it = 0..7.
// Reads t3 bf16 from out's row slot, then overwrites the slot with the
// final fp32 row (read precedes write in-thread; waves own disjoint rows).
// ---------------------------------------------------------------------------
__global__ __launch_bounds__(256, 4) void combine(const float* __restrict__ x,
                                                  const float* __restrict__ w7,
                                                  const float* __restrict__ zp,
                                                  float* __restrict__ out) {
    const int bid = blockIdx.x;
    const int nh  = ((bid & 7) << 8) | (bid >> 3);   // same swizzle as t3gemm
    const int n   = nh >> 7;
    const int h   = nh & (HH - 1);
    const int tid = threadIdx.x;
    const int lane = tid & 63;

    const int w0  = (tid & 31) * 4;
    const int chi = tid >> 5;           // c = it*8 + chi
    const bool isw = (w0 == 0);
    const int src  = lane | 31;         // shfl source for roll-wrap values

    const float* p[9];
    int s[9];
    const float* xb0 = x + (((size_t)(n * CC + chi)) * HH) * WW;
    #pragma unroll
    for (int r = 0; r < 3; ++r) {
        int hh = h + r - 1;
        bool hok = (unsigned)hh < HH;
        #pragma unroll
        for (int q = 0; q < 3; ++q) {
            int cb = w0 - 4 + q * 4;
            bool ok = hok && (unsigned)cb < WW;
            p[r * 3 + q] = ok ? (xb0 + (size_t)hh * WW + cb) : zp;
            s[r * 3 + q] = ok ? (8 * HH * WW) : 0;
        }
    }
    const float* wcp = w7 + chi * 9;
    const short* t3s = (const short*)out;
    size_t t3o = ((size_t)(n * CC + chi) * HH + h) * 256 + w0;
    float* outp = out + ((((size_t)(n * CC + chi)) * HH + h) * WW) + w0;

    #pragma unroll
    for (int it = 0; it < 8; ++it) {
        float4 cur[9];
        #pragma unroll
        for (int t = 0; t < 9; ++t) { cur[t] = *(const float4*)p[t]; p[t] += s[t]; }
        float wc[9];
        #pragma unroll
        for (int t = 0; t < 9; ++t) wc[t] = wcp[t];
        ushort4 tv = *(const ushort4*)&t3s[t3o];

        // window view: win[r][q*4+k] = col w0-4+q*4+k of row h+r-1
        float win[3][12];
        #pragma unroll
        for (int r = 0; r < 3; ++r) {
            #pragma unroll
            for (int q = 0; q < 3; ++q) {
                float4 v = cur[r * 3 + q];
                win[r][q * 4 + 0] = v.x; win[r][q * 4 + 1] = v.y;
                win[r][q * 4 + 2] = v.z; win[r][q * 4 + 3] = v.w;
            }
        }
        // wrap values (w==0 roll): cols 125,127 live in lane (lane|31)'s q=1 quad
        float wrap0[3], wrap1[3];
        #pragma unroll
        for (int r = 0; r < 3; ++r) {
            wrap0[r] = __shfl(win[r][5], src);
            wrap1[r] = __shfl(win[r][7], src);
        }

        float t3v[4] = {bf2f(tv.x), bf2f(tv.y), bf2f(tv.z), bf2f(tv.w)};

        float res[4];
        #pragma unroll
        for (int e = 0; e < 4; ++e) {
            float a = 0.f;
            #pragma unroll
            for (int j = 0; j < 3; ++j) {
                #pragma unroll
                for (int i = 0; i < 3; ++i) {
                    float lhs = win[1][e + 2 * i + 2];        // col w+2(i-1)
                    float rhs = win[i][e + 2 * j + 1];        // col w+2j-3
                    if (e == 0)
                        rhs = isw ? ((j == 0) ? wrap0[i]
                                   : (j == 1) ? wrap1[i] : 0.f)
                                  : rhs;
                    a = fmaf(wc[j * 3 + i], fmaxf(lhs, rhs), a);
                }
            }
            res[e] = a;
        }
        float4 o;
        o.x = res[0] * t3v[0]; o.y = res[1] * t3v[1];
        o.z = res[2] * t3v[2]; o.w = res[3] * t3v[3];
        *(float4*)outp = o;          // overwrites this row's t3 slot (safe:
                                     // tv consumed above forces load-before-store)

        // advance per-iteration state (8 channels per iteration step)
        wcp  += 8 * 9;
        t3o  += (size_t)8 * HH * 256;
        outp += (size_t)8 * HH * WW;
    }
}

extern "C" void kernel_launch(void* const* d_in, const int* in_sizes, int n_in,
                              void* d_out, int out_size, void* d_ws, size_t ws_size,
                              hipStream_t stream) {
    const float* x  = (const float*)d_in[0];
    const float* w3 = (const float*)d_in[1];
    const float* w7 = (const float*)d_in[2];
    float* out = (float*)d_out;

    short* Abf = (short*)d_ws;                    // 40960 B bf16 weights
    float* zp  = (float*)((char*)d_ws + 40960);   // 256 B zero page

    prep_w<<<(CC * CC * 5 + 255) / 256, 256, 0, stream>>>(w3, Abf, zp);
    t3gemm<<<NN * HH, 256, 0, stream>>>(x, Abf, out);
    combine<<<NN * HH, 256, 0, stream>>>(x, w7, zp, out);
}

// Round 4
// 162.024 us; speedup vs baseline: 1.0997x; 1.0997x over previous
//
#include <hip/hip_runtime.h>

// Problem constants (frozen by the reference)
#define NN 16
#define CC 64
#define HH 128
#define WW 128

#define LDS_STRIDE 72    // bf16 elems per xsT panel row (144 B; dword stride 36)
#define PANEL_DW   4752  // dwords per panel (19008 B)
#define PANEL_SH   9504  // shorts per panel

typedef __attribute__((ext_vector_type(8))) short short8;   // bf16x8 (4 VGPRs)
typedef __attribute__((ext_vector_type(4))) float floatx4;  // MFMA C/D

__device__ __forceinline__ short f2bf(float f) {
    union { float f; unsigned u; } v; v.f = f;
    unsigned r = v.u + 0x7fffu + ((v.u >> 16) & 1u);
    return (short)(r >> 16);
}
__device__ __forceinline__ unsigned pack2bf(float lo, float hi) {
    union { float f; unsigned u; } a, b; a.f = lo; b.f = hi;
    unsigned ra = a.u + 0x7fffu + ((a.u >> 16) & 1u);
    unsigned rb = b.u + 0x7fffu + ((b.u >> 16) & 1u);
    return (ra >> 16) | (rb & 0xffff0000u);
}
__device__ __forceinline__ float bf2f(unsigned short u) {
    union { unsigned u; float f; } v; v.u = ((unsigned)u) << 16;
    return v.f;
}

// ---------------------------------------------------------------------------
// Kernel 0: w3 (co, ci, 1, 5) fp32 -> Abf[co][kk] bf16, kk = tap*64 + ci.
// Also zeroes the 256 B zero-page used by combine's OOB window loads
// (d_ws is re-poisoned before every launch, so rewrite every call).
// ---------------------------------------------------------------------------
__global__ __launch_bounds__(256) void prep_w(const float* __restrict__ w3,
                                              short* __restrict__ Abf,
                                              float* __restrict__ zp) {
    int idx = blockIdx.x * 256 + threadIdx.x;
    if (idx < CC * CC * 5) {
        int tap = idx % 5;
        int ci  = (idx / 5) % CC;
        int co  = idx / (5 * CC);
        Abf[co * 320 + tap * 64 + ci] = f2bf(w3[idx]);
    }
    if (blockIdx.x == 0 && threadIdx.x < 64) zp[threadIdx.x] = 0.f;
}

// ---------------------------------------------------------------------------
// Kernel 1: t3 GEMM. One block per (n, h-PAIR); 1024 blocks; LDS 38016 B
// (two 19008 B row panels) -> 4 blocks/CU.
// Phase 1 (coalesced gather): rows h,h+1 are contiguous, so one wave-instr
//   reads 1024 CONTIGUOUS bytes of one channel (lane = row*32 + w-quad).
//   Each lane loads channels 2cp and 2cp+1 at the same (row, w-quad) ->
//   pack2bf pairs in-lane, no shuffles. The transpose cost moves from
//   64-line scattered global loads (invisible latency serialization) to
//   16-way LDS write conflicts (~3 us total, visible in the counter).
// Phase 2: per row sequentially, MFMA with the round-1-proven 2x2 wave
//   split (co-half x w-half). acc stays 32 VGPRs.
// Store: t3[n][co][h][w] bf16 -> first 256 B of out's 512 B row slot.
// ---------------------------------------------------------------------------
__global__ __launch_bounds__(256, 4) void t3gemm(const float* __restrict__ x,
                                                 const short* __restrict__ Abf,
                                                 float* __restrict__ out) {
    __shared__ __align__(16) char smem[2 * 19008];   // 38016 B
    short*    xsT = (short*)smem;
    unsigned* xsW = (unsigned*)smem;   // dword view

    const int bid = blockIdx.x;
    const int rp  = ((bid & 7) << 7) | (bid >> 3);   // XCD-contiguous row pair
    const int n   = rp >> 6;
    const int h   = (rp & 63) * 2;                   // rows h, h+1
    const int tid = threadIdx.x;
    const int lane = tid & 63;
    const int W    = tid >> 6;

    // ---- Phase 1: coalesced load + in-lane pack + transposed LDS write ----
    {
        const int ri = lane >> 5;        // row within pair
        const int wq = lane & 31;        // w-quad
        unsigned* panel = xsW + ri * PANEL_DW;
        #pragma unroll
        for (int i = 0; i < 8; ++i) {
            const int cp = W * 8 + i;    // channel pair cp: ch 2cp, 2cp+1
            const float* b0 = x + (((size_t)(n * CC + 2 * cp)) * HH + h) * WW;
            float4 av = *(const float4*)(b0 + lane * 4);            // ch 2cp
            float4 bv = *(const float4*)(b0 + HH * WW + lane * 4);  // ch 2cp+1
            #pragma unroll
            for (int k = 0; k < 4; ++k) {
                int wp = wq * 4 + 2 + k;
                panel[wp * 36 + cp] = pack2bf(av[k], bv[k]);
            }
        }
        // zero pad rows wp in {0,1,130,131} of both panels
        {
            int pi  = tid >> 7;          // panel
            int idx = tid & 127;
            int wpi = idx >> 5;
            int wpz = (wpi < 2) ? wpi : 128 + wpi;
            xsW[pi * PANEL_DW + wpz * 36 + (idx & 31)] = 0u;
        }
    }
    __syncthreads();

    // ---- Phase 2: MFMA, 2x2 wave split, rows sequential ----
    const int lm = lane & 15;
    const int g  = lane >> 4;
    const int mh = W >> 1;           // co half: co-tiles {2mh, 2mh+1}
    const int wh = W & 1;            // w half:  j-tiles wh*4 .. wh*4+3

    const short* arow = Abf + (mh * 32 + lm) * 320;
    short* t3s = (short*)out;

    #pragma unroll
    for (int row = 0; row < 2; ++row) {
        const short* panel = xsT + row * PANEL_SH;

        floatx4 acc[2][4];
        #pragma unroll
        for (int m = 0; m < 2; ++m)
            #pragma unroll
            for (int j = 0; j < 4; ++j) acc[m][j] = (floatx4){0.f, 0.f, 0.f, 0.f};

        for (int ks = 0; ks < 10; ++ks) {
            const int kbase = ks * 32 + g * 8;
            const int tap   = kbase >> 6;
            const int cib   = kbase & 63;

            short8 a0 = *(const short8*)(arow + kbase);
            short8 a1 = *(const short8*)(arow + 16 * 320 + kbase);
            #pragma unroll
            for (int j = 0; j < 4; ++j) {
                int wp = (wh * 4 + j) * 16 + lm + tap;
                short8 b = *(const short8*)&panel[wp * LDS_STRIDE + cib];
                acc[0][j] = __builtin_amdgcn_mfma_f32_16x16x32_bf16(a0, b, acc[0][j], 0, 0, 0);
                acc[1][j] = __builtin_amdgcn_mfma_f32_16x16x32_bf16(a1, b, acc[1][j], 0, 0, 0);
            }
        }

        // store this row's t3 (bf16) into out's row slots
        #pragma unroll
        for (int m = 0; m < 2; ++m)
            #pragma unroll
            for (int j = 0; j < 4; ++j)
                #pragma unroll
                for (int r = 0; r < 4; ++r) {
                    int co = (mh * 2 + m) * 16 + g * 4 + r;
                    int w  = (wh * 4 + j) * 16 + lm;
                    t3s[((size_t)(n * CC + co) * HH + (h + row)) * 256 + w] =
                        f2bf(acc[m][j][r]);
                }
    }
}

// ---------------------------------------------------------------------------
// Kernel 2: combine. One block per (n,h) row. NO LDS, NO barriers; near its
// BW roofline already (~166 MB HBM). Thread owns (chi = tid>>5, w0);
// iterates c = it*8 + chi. Reads t3 bf16 from out's row slot, then
// overwrites the slot with the final fp32 row (read precedes write
// in-thread; waves own disjoint rows).
// ---------------------------------------------------------------------------
__global__ __launch_bounds__(256, 4) void combine(const float* __restrict__ x,
                                                  const float* __restrict__ w7,
                                                  const float* __restrict__ zp,
                                                  float* __restrict__ out) {
    const int bid = blockIdx.x;
    const int nh  = ((bid & 7) << 8) | (bid >> 3);
    const int n   = nh >> 7;
    const int h   = nh & (HH - 1);
    const int tid = threadIdx.x;
    const int lane = tid & 63;

    const int w0  = (tid & 31) * 4;
    const int chi = tid >> 5;           // c = it*8 + chi
    const bool isw = (w0 == 0);
    const int src  = lane | 31;         // shfl source for roll-wrap values

    const float* p[9];
    int s[9];
    const float* xb0 = x + (((size_t)(n * CC + chi)) * HH) * WW;
    #pragma unroll
    for (int r = 0; r < 3; ++r) {
        int hh = h + r - 1;
        bool hok = (unsigned)hh < HH;
        #pragma unroll
        for (int q = 0; q < 3; ++q) {
            int cb = w0 - 4 + q * 4;
            bool ok = hok && (unsigned)cb < WW;
            p[r * 3 + q] = ok ? (xb0 + (size_t)hh * WW + cb) : zp;
            s[r * 3 + q] = ok ? (8 * HH * WW) : 0;
        }
    }
    const float* wcp = w7 + chi * 9;
    const short* t3s = (const short*)out;
    size_t t3o = ((size_t)(n * CC + chi) * HH + h) * 256 + w0;
    float* outp = out + ((((size_t)(n * CC + chi)) * HH + h) * WW) + w0;

    #pragma unroll
    for (int it = 0; it < 8; ++it) {
        float4 cur[9];
        #pragma unroll
        for (int t = 0; t < 9; ++t) { cur[t] = *(const float4*)p[t]; p[t] += s[t]; }
        float wc[9];
        #pragma unroll
        for (int t = 0; t < 9; ++t) wc[t] = wcp[t];
        ushort4 tv = *(const ushort4*)&t3s[t3o];

        // window view: win[r][q*4+k] = col w0-4+q*4+k of row h+r-1
        float win[3][12];
        #pragma unroll
        for (int r = 0; r < 3; ++r) {
            #pragma unroll
            for (int q = 0; q < 3; ++q) {
                float4 v = cur[r * 3 + q];
                win[r][q * 4 + 0] = v.x; win[r][q * 4 + 1] = v.y;
                win[r][q * 4 + 2] = v.z; win[r][q * 4 + 3] = v.w;
            }
        }
        // wrap values (w==0 roll): cols 125,127 live in lane (lane|31)'s q=1 quad
        float wrap0[3], wrap1[3];
        #pragma unroll
        for (int r = 0; r < 3; ++r) {
            wrap0[r] = __shfl(win[r][5], src);
            wrap1[r] = __shfl(win[r][7], src);
        }

        float t3v[4] = {bf2f(tv.x), bf2f(tv.y), bf2f(tv.z), bf2f(tv.w)};

        float res[4];
        #pragma unroll
        for (int e = 0; e < 4; ++e) {
            float a = 0.f;
            #pragma unroll
            for (int j = 0; j < 3; ++j) {
                #pragma unroll
                for (int i = 0; i < 3; ++i) {
                    float lhs = win[1][e + 2 * i + 2];        // col w+2(i-1)
                    float rhs = win[i][e + 2 * j + 1];        // col w+2j-3
                    if (e == 0)
                        rhs = isw ? ((j == 0) ? wrap0[i]
                                   : (j == 1) ? wrap1[i] : 0.f)
                                  : rhs;
                    a = fmaf(wc[j * 3 + i], fmaxf(lhs, rhs), a);
                }
            }
            res[e] = a;
        }
        float4 o;
        o.x = res[0] * t3v[0]; o.y = res[1] * t3v[1];
        o.z = res[2] * t3v[2]; o.w = res[3] * t3v[3];
        *(float4*)outp = o;          // overwrites this row's t3 slot (safe:
                                     // tv consumed above forces load-before-store)

        // advance per-iteration state (8 channels per iteration step)
        wcp  += 8 * 9;
        t3o  += (size_t)8 * HH * 256;
        outp += (size_t)8 * HH * WW;
    }
}

extern "C" void kernel_launch(void* const* d_in, const int* in_sizes, int n_in,
                              void* d_out, int out_size, void* d_ws, size_t ws_size,
                              hipStream_t stream) {
    const float* x  = (const float*)d_in[0];
    const float* w3 = (const float*)d_in[1];
    const float* w7 = (const float*)d_in[2];
    float* out = (float*)d_out;

    short* Abf = (short*)d_ws;                    // 40960 B bf16 weights
    float* zp  = (float*)((char*)d_ws + 40960);   // 256 B zero page

    prep_w<<<(CC * CC * 5 + 255) / 256, 256, 0, stream>>>(w3, Abf, zp);
    t3gemm<<<NN * HH / 2, 256, 0, stream>>>(x, Abf, out);
    combine<<<NN * HH, 256, 0, stream>>>(x, w7, zp, out);
}